// Round 5
// baseline (446.464 us; speedup 1.0000x reference)
//
#include <hip/hip_runtime.h>

#define N_NODES 8192
#define IN_F 256
#define OUT_F 128
#define ALPHA 0.5f
#define JC 8
#define KCHUNK 1024            // N_NODES / JC
#define RK 32                  // k-window per round (one MFMA K-step)
#define ROUNDS 32              // KCHUNK / RK

using short8 = __attribute__((ext_vector_type(8))) short;
using f32x4  = __attribute__((ext_vector_type(4))) float;

__device__ __forceinline__ unsigned int f2bf(float f){
  unsigned int u = __float_as_uint(f);
  u += 0x7fffu + ((u >> 16) & 1u);   // RNE
  return u >> 16;
}

// async global->LDS DMA, 16B per lane. lds dest must be wave-uniform base
// + lane*16 (HW scatter) — pass per-lane ptr consistent with that.
__device__ __forceinline__ void gld16(const void* g, void* l){
  __builtin_amdgcn_global_load_lds(
      (const __attribute__((address_space(1))) unsigned int*)g,
      (__attribute__((address_space(3))) unsigned int*)l, 16, 0, 0);
}

// ---------------- K0: h = x @ W (fp32) ----------------
__global__ __launch_bounds__(256) void k_h(const float* __restrict__ x,
                                           const float* __restrict__ W,
                                           float* __restrict__ h){
  __shared__ float xs[16*IN_F];
  const int tid = threadIdx.x;
  const int r0 = blockIdx.x * 16;
  const float4* xg = (const float4*)(x + (size_t)r0*IN_F);
  float4* xl = (float4*)xs;
  #pragma unroll
  for(int i=0;i<4;i++) xl[tid + i*256] = xg[tid + i*256];
  __syncthreads();
  const int wave = tid >> 6, lane = tid & 63;
  float2 acc[4];
  #pragma unroll
  for(int j=0;j<4;j++){ acc[j].x = 0.f; acc[j].y = 0.f; }
  const float2* Wp = (const float2*)W;
  for(int k4=0;k4<IN_F;k4+=4){
    float4 xq[4];
    #pragma unroll
    for(int j=0;j<4;j++) xq[j] = *(const float4*)&xs[(wave*4+j)*IN_F + k4];
    #pragma unroll
    for(int kk=0;kk<4;kk++){
      float2 wv = Wp[(size_t)(k4+kk)*64 + lane];
      #pragma unroll
      for(int j=0;j<4;j++){
        float xv = kk==0?xq[j].x : kk==1?xq[j].y : kk==2?xq[j].z : xq[j].w;
        acc[j].x += xv*wv.x; acc[j].y += xv*wv.y;
      }
    }
  }
  #pragma unroll
  for(int j=0;j<4;j++)
    *(float2*)(h + (size_t)(r0 + wave*4 + j)*OUT_F + lane*2) = acc[j];
}

// ---------------- K1: f1 = h@a1, f2 = h@a2 ----------------
__global__ __launch_bounds__(256) void k_f(const float* __restrict__ h,
                                           const float* __restrict__ a,
                                           float* __restrict__ f1,
                                           float* __restrict__ f2){
  const int wave = threadIdx.x >> 6, lane = threadIdx.x & 63;
  const int row = blockIdx.x*4 + wave;
  float2 hv = ((const float2*)(h + (size_t)row*OUT_F))[lane];
  float2 a1 = ((const float2*)a)[lane];
  float2 a2 = ((const float2*)(a + OUT_F))[lane];
  float s1 = hv.x*a1.x + hv.y*a1.y;
  float s2 = hv.x*a2.x + hv.y*a2.y;
  #pragma unroll
  for(int off=32; off; off>>=1){
    s1 += __shfl_down(s1, off);
    s2 += __shfl_down(s2, off);
  }
  if(lane == 0){ f1[row] = s1; f2[row] = s2; }
}

// ---------------- K2: pack h into MFMA-B fragment-major bf16 ----------------
// P short idx ((kb*8+c)*64+lane)*8+t = bf16(h[kb*32+(lane>>4)*8+t][c*16+(lane&15)])
#define LDW 132
__global__ __launch_bounds__(256) void k_pack(const float* __restrict__ h,
                                              unsigned short* __restrict__ P){
  __shared__ float ld[32*LDW];
  const int tid = threadIdx.x;
  const int kb = blockIdx.x, j0 = kb*32;
  #pragma unroll
  for(int i=0;i<4;i++){
    int idx = tid + i*256;
    int row = idx >> 5, c4 = (idx & 31)*4;
    *(float4*)&ld[row*LDW + c4] = *(const float4*)(h + (size_t)(j0+row)*OUT_F + c4);
  }
  __syncthreads();
  #pragma unroll
  for(int i=0;i<2;i++){
    int o = tid*2 + i;
    int c = o >> 6, lane = o & 63;
    int q = lane >> 4, n = lane & 15;
    short8 v;
    #pragma unroll
    for(int t=0;t<8;t++) v[t] = (short)f2bf(ld[(q*8+t)*LDW + c*16 + n]);
    *(short8*)(P + ((size_t)(kb*8 + c)*64 + lane)*8) = v;
  }
}

// ---------------- K3: async-DMA double-buffered fused attn ----------------
// grid (JC=8, 64) x 256 thr, 2 blocks/CU (LDS ~53KB). Per 32-k round:
//   top of round: global_load_lds DMA of next round's raw adj tile (16KB,
//   XOR-swizzled via SOURCE address) + B tile (8KB) into the spare buffer.
//   compute: raw adj from LDS -> w=mask*exp (in-register, exact A-frag
//   layout) -> 16 MFMA. One barrier/round; vmcnt(0) drain sits after a full
//   round of compute -> memory queue never empties.
__global__ __launch_bounds__(256, 2) void k_attn(const int* __restrict__ adj,
    const unsigned short* __restrict__ P,
    const float* __restrict__ f1, const float* __restrict__ f2,
    float* __restrict__ part, float* __restrict__ denp){
  __shared__ __align__(16) char Alds[2][16384];   // raw adj, [row(128)][slot(8)*16B]
  __shared__ __align__(16) char Blds[2][8192];    // fragment-major bf16
  __shared__ float f2s[KCHUNK];
  __shared__ float f1s[128];
  const int tid = threadIdx.x;
  const int wave = tid >> 6, lane = tid & 63;
  const int m = lane & 15, q = lane >> 4;
  const int jc = blockIdx.x;                 // linear id % 8 -> XCD-pinned
  const int r0b = blockIdx.y * 128;
  const int jb = jc * KCHUNK;

  // prologue: f1/f2 slices to LDS
  ((float4*)f2s)[tid] = ((const float4*)(f2 + jb))[tid];
  if(tid < 128) f1s[tid] = f1[r0b + tid];

  // DMA source pointers (per-thread, fixed; advance by round offset)
  const int g = (lane & 7) ^ (lane >> 3);    // XOR-swizzled source granule
  const char* asrc[4];
  #pragma unroll
  for(int i=0;i<4;i++){
    int rowid = (wave*4 + i)*8 + (lane >> 3);
    asrc[i] = (const char*)(adj + (size_t)(r0b + rowid)*N_NODES + jb) + g*16;
  }
  const char* bsrc[2];
  #pragma unroll
  for(int i=0;i<2;i++)
    bsrc[i] = (const char*)P + (size_t)jc*ROUNDS*8192 + ((size_t)(wave*2+i)*64 + lane)*16;

  auto issue_dma = [&](int rd, int buf){
    #pragma unroll
    for(int i=0;i<4;i++)
      gld16(asrc[i] + (size_t)rd*128, Alds[buf] + (wave*4+i)*1024 + lane*16);
    #pragma unroll
    for(int i=0;i<2;i++)
      gld16(bsrc[i] + (size_t)rd*8192, Blds[buf] + (wave*2+i)*1024 + lane*16);
  };

  issue_dma(0, 0);

  f32x4 acc0[8], acc1[8];
  #pragma unroll
  for(int c=0;c<8;c++){ acc0[c] = (f32x4){0,0,0,0}; acc1[c] = (f32x4){0,0,0,0}; }
  float den0 = 0.f, den1 = 0.f;

  const int rg0 = wave*32 + m;               // block-local rows rg0, rg0+16
  const int xr = m & 7;
  const int s0 = (q*2) ^ xr, s1 = s0 ^ 1;    // swizzled 16B slots for k=q*8..+7

  __syncthreads();                           // f1s/f2s ready (+ rd0 DMA drained)
  const float rf1a = f1s[rg0];
  const float rf1b = f1s[rg0 + 16];

  auto wcalc = [&](int4 alo, int4 ahi, float4 fva, float4 fvb,
                   float rf1, float& den) -> short8 {
    short8 af; float t, w;
    #define WE(slot, av, fv)                              \
      t = rf1 + (fv); t = fmaxf(t, ALPHA*t);              \
      w = ((av) > 0) ? __expf(t) : 0.f;                   \
      den += w; af[slot] = (short)f2bf(w);
    WE(0,alo.x,fva.x) WE(1,alo.y,fva.y) WE(2,alo.z,fva.z) WE(3,alo.w,fva.w)
    WE(4,ahi.x,fvb.x) WE(5,ahi.y,fvb.y) WE(6,ahi.z,fvb.z) WE(7,ahi.w,fvb.w)
    #undef WE
    return af;
  };

  for(int rd=0; rd<ROUNDS; rd++){
    const int buf = rd & 1;
    if(rd+1 < ROUNDS) issue_dma(rd+1, buf ^ 1);
    // ---- compute from buf (LDS only) ----
    const int4* Arow0 = (const int4*)(Alds[buf] + rg0*128);
    const int4* Arow1 = (const int4*)(Alds[buf] + (rg0+16)*128);
    int4 alo0 = Arow0[s0], ahi0 = Arow0[s1];
    int4 alo1 = Arow1[s0], ahi1 = Arow1[s1];
    float4 fva = *(const float4*)(f2s + rd*RK + q*8);
    float4 fvb = *(const float4*)(f2s + rd*RK + q*8 + 4);
    short8 af0 = wcalc(alo0, ahi0, fva, fvb, rf1a, den0);
    short8 af1 = wcalc(alo1, ahi1, fva, fvb, rf1b, den1);
    const short8* Bl = (const short8*)(Blds[buf]) + lane;
    #pragma unroll
    for(int c=0;c<8;c++){
      short8 Bf = Bl[c*64];
      acc0[c] = __builtin_amdgcn_mfma_f32_16x16x32_bf16(af0, Bf, acc0[c], 0,0,0);
      acc1[c] = __builtin_amdgcn_mfma_f32_16x16x32_bf16(af1, Bf, acc1[c], 0,0,0);
    }
    __syncthreads();   // drains this round's DMA; protects buffer swap
  }

  // den: lanes m,m+16,m+32,m+48 hold q-partials of row m
  den0 += __shfl_down(den0, 32); den0 += __shfl_down(den0, 16);
  den1 += __shfl_down(den1, 32); den1 += __shfl_down(den1, 16);
  const int r0w = r0b + wave*32;
  if(lane < 16){
    denp[(size_t)jc*N_NODES + r0w + lane]      = den0;
    denp[(size_t)jc*N_NODES + r0w + 16 + lane] = den1;
  }
  // C/D layout: col = c*16 + m, row = q*4 + reg (verified R1-R4)
  float* pp = part + (size_t)jc*N_NODES*OUT_F;
  #pragma unroll
  for(int c=0;c<8;c++){
    #pragma unroll
    for(int reg=0;reg<4;reg++){
      pp[(size_t)(r0w + q*4 + reg)*OUT_F      + c*16 + m] = acc0[c][reg];
      pp[(size_t)(r0w + 16 + q*4 + reg)*OUT_F + c*16 + m] = acc1[c][reg];
    }
  }
}

// ---------------- K4: out = elu(sum(parts)/sum(dens)) ----------------
__global__ __launch_bounds__(256) void k_out(const float* __restrict__ part,
    const float* __restrict__ denp, float* __restrict__ out){
  const int idx = blockIdx.x*256 + threadIdx.x;
  const int r = idx >> 7;
  float v = 0.f, d = 0.f;
  #pragma unroll
  for(int p=0;p<JC;p++){
    v += part[(size_t)p*N_NODES*OUT_F + idx];
    d += denp[(size_t)p*N_NODES + r];
  }
  v /= d;
  out[idx] = v > 0.f ? v : (__expf(v) - 1.f);
}

extern "C" void kernel_launch(void* const* d_in, const int* in_sizes, int n_in,
                              void* d_out, int out_size, void* d_ws, size_t ws_size,
                              hipStream_t stream){
  const float* x   = (const float*)d_in[0];
  const int*   adj = (const int*)d_in[1];
  const float* W   = (const float*)d_in[2];
  const float* a   = (const float*)d_in[3];
  char* ws = (char*)d_ws;
  float* h            = (float*)ws;
  unsigned short* P   = (unsigned short*)(ws + (4u<<20));
  float* f1           = (float*)(ws + (6u<<20));
  float* f2           = (float*)(ws + (6u<<20) + (32u<<10));
  float* part         = (float*)(ws + (8u<<20));
  float* denp         = (float*)(ws + (40u<<20));
  float* out          = (float*)d_out;

  k_h<<<512, 256, 0, stream>>>(x, W, h);
  k_f<<<2048, 256, 0, stream>>>(h, a, f1, f2);
  k_pack<<<256, 256, 0, stream>>>(h, P);
  k_attn<<<dim3(JC,64), 256, 0, stream>>>(adj, P, f1, f2, part, denp);
  k_out<<<(N_NODES*OUT_F)/256, 256, 0, stream>>>(part, denp, out);
}

// Round 6
// 441.040 us; speedup vs baseline: 1.0123x; 1.0123x over previous
//
#include <hip/hip_runtime.h>

#define N_NODES 8192
#define IN_F 256
#define OUT_F 128
#define ALPHA 0.5f
#define JC 8
#define KCHUNK 1024            // N_NODES / JC
#define ROUNDS 32              // KCHUNK / 32

using short8 = __attribute__((ext_vector_type(8))) short;
using f32x4  = __attribute__((ext_vector_type(4))) float;

__device__ __forceinline__ unsigned int f2bf(float f){
  unsigned int u = __float_as_uint(f);
  u += 0x7fffu + ((u >> 16) & 1u);   // RNE
  return u >> 16;
}

// ---------------- K0: h = x @ W (fp32) ----------------
__global__ __launch_bounds__(256) void k_h(const float* __restrict__ x,
                                           const float* __restrict__ W,
                                           float* __restrict__ h){
  __shared__ float xs[16*IN_F];
  const int tid = threadIdx.x;
  const int r0 = blockIdx.x * 16;
  const float4* xg = (const float4*)(x + (size_t)r0*IN_F);
  float4* xl = (float4*)xs;
  #pragma unroll
  for(int i=0;i<4;i++) xl[tid + i*256] = xg[tid + i*256];
  __syncthreads();
  const int wave = tid >> 6, lane = tid & 63;
  float2 acc[4];
  #pragma unroll
  for(int j=0;j<4;j++){ acc[j].x = 0.f; acc[j].y = 0.f; }
  const float2* Wp = (const float2*)W;
  for(int k4=0;k4<IN_F;k4+=4){
    float4 xq[4];
    #pragma unroll
    for(int j=0;j<4;j++) xq[j] = *(const float4*)&xs[(wave*4+j)*IN_F + k4];
    #pragma unroll
    for(int kk=0;kk<4;kk++){
      float2 wv = Wp[(size_t)(k4+kk)*64 + lane];
      #pragma unroll
      for(int j=0;j<4;j++){
        float xv = kk==0?xq[j].x : kk==1?xq[j].y : kk==2?xq[j].z : xq[j].w;
        acc[j].x += xv*wv.x; acc[j].y += xv*wv.y;
      }
    }
  }
  #pragma unroll
  for(int j=0;j<4;j++)
    *(float2*)(h + (size_t)(r0 + wave*4 + j)*OUT_F + lane*2) = acc[j];
}

// ---------------- K1: f1 = h@a1, f2 = h@a2 ----------------
__global__ __launch_bounds__(256) void k_f(const float* __restrict__ h,
                                           const float* __restrict__ a,
                                           float* __restrict__ f1,
                                           float* __restrict__ f2){
  const int wave = threadIdx.x >> 6, lane = threadIdx.x & 63;
  const int row = blockIdx.x*4 + wave;
  float2 hv = ((const float2*)(h + (size_t)row*OUT_F))[lane];
  float2 a1 = ((const float2*)a)[lane];
  float2 a2 = ((const float2*)(a + OUT_F))[lane];
  float s1 = hv.x*a1.x + hv.y*a1.y;
  float s2 = hv.x*a2.x + hv.y*a2.y;
  #pragma unroll
  for(int off=32; off; off>>=1){
    s1 += __shfl_down(s1, off);
    s2 += __shfl_down(s2, off);
  }
  if(lane == 0){ f1[row] = s1; f2[row] = s2; }
}

// ---------------- K2: pack h into MFMA-B fragment-major bf16 ----------------
// P short idx ((kb*8+c)*64+lane)*8+t = bf16(h[kb*32+(lane>>4)*8+t][c*16+(lane&15)])
#define LDW 132
__global__ __launch_bounds__(256) void k_pack(const float* __restrict__ h,
                                              unsigned short* __restrict__ P){
  __shared__ float ld[32*LDW];
  const int tid = threadIdx.x;
  const int kb = blockIdx.x, j0 = kb*32;
  #pragma unroll
  for(int i=0;i<4;i++){
    int idx = tid + i*256;
    int row = idx >> 5, c4 = (idx & 31)*4;
    *(float4*)&ld[row*LDW + c4] = *(const float4*)(h + (size_t)(j0+row)*OUT_F + c4);
  }
  __syncthreads();
  #pragma unroll
  for(int i=0;i<2;i++){
    int o = tid*2 + i;
    int c = o >> 6, lane = o & 63;
    int q = lane >> 4, n = lane & 15;
    short8 v;
    #pragma unroll
    for(int t=0;t<8;t++) v[t] = (short)f2bf(ld[(q*8+t)*LDW + c*16 + n]);
    *(short8*)(P + ((size_t)(kb*8 + c)*64 + lane)*8) = v;
  }
}

// ---------------- K2b: compress adj (268MB) -> bitmask (8MB) ---------------
// Flat linear stream, perfectly coalesced: wave reads 64 consecutive ints,
// __ballot -> one uint64. This is the ONLY kernel that touches adj.
__global__ __launch_bounds__(256) void k_comp(const int* __restrict__ adj,
                                              unsigned long long* __restrict__ bm){
  const int lane = threadIdx.x & 63;
  const int wid = (blockIdx.x*256 + threadIdx.x) >> 6;
  const int nw = (gridDim.x*256) >> 6;
  const size_t total = (size_t)N_NODES*N_NODES;
  for(size_t base = (size_t)wid*512; base < total; base += (size_t)nw*512){
    unsigned long long msk[8];
    #pragma unroll
    for(int u=0;u<8;u++){
      int v = adj[base + (size_t)u*64 + lane];
      msk[u] = __ballot(v > 0);
    }
    if(lane < 8){
      unsigned long long v = msk[0];
      #pragma unroll
      for(int u=1;u<8;u++) v = (lane == u) ? msk[u] : v;
      bm[base/64 + lane] = v;
    }
  }
}

// ---------------- K3: bitmask-driven fused attn (barrier-free k-loop) ------
// grid (JC=8, 64) x 256 thr, 2 blocks/CU. Per block: 128 rows x KCHUNK k.
// Adjacency = 16KB bitmask tile in LDS (bank-swizzled). B-frags are direct
// 1KB coalesced loads from P (L2-resident per XCD; jc == blockId%8 pins the
// 256KB P-chunk + 1MB bitmask column per XCD). Register prefetch 1 round.
__global__ __launch_bounds__(256, 2) void k_attn(
    const unsigned int* __restrict__ bmw,   // bitmask, uint32 view: [row][256]
    const unsigned short* __restrict__ P,
    const float* __restrict__ f1, const float* __restrict__ f2,
    float* __restrict__ part, float* __restrict__ denp){
  __shared__ unsigned int bs[128*32];   // word(row,wd) at row*32 + (wd^(row&31))
  __shared__ float f2s[KCHUNK];
  __shared__ float f1s[128];
  const int tid = threadIdx.x;
  const int wave = tid >> 6, lane = tid & 63;
  const int m = lane & 15, q = lane >> 4;
  const int jc = blockIdx.x;
  const int r0b = blockIdx.y * 128;

  // prologue: f2 chunk (4KB), f1 (512B), bitmask tile (16KB, swizzled)
  ((float4*)f2s)[tid] = ((const float4*)(f2 + jc*KCHUNK))[tid];
  if(tid < 128) f1s[tid] = f1[r0b + tid];
  {
    const int row = tid >> 1, h16 = (tid & 1) * 16;
    const unsigned int* src = bmw + (size_t)(r0b + row)*256 + jc*32 + h16;
    const int sw = row & 31;
    #pragma unroll
    for(int i=0;i<16;i+=4){
      uint4 v = *(const uint4*)(src + i);
      bs[row*32 + ((h16+i  ) ^ sw)] = v.x;
      bs[row*32 + ((h16+i+1) ^ sw)] = v.y;
      bs[row*32 + ((h16+i+2) ^ sw)] = v.z;
      bs[row*32 + ((h16+i+3) ^ sw)] = v.w;
    }
  }
  __syncthreads();

  const int rg0 = wave*32 + m;
  const float rf1a = f1s[rg0], rf1b = f1s[rg0 + 16];
  const unsigned int* bw0 = &bs[rg0*32];
  const unsigned int* bw1 = &bs[(rg0+16)*32];
  const int x0 = rg0 & 31, x1 = (rg0+16) & 31;
  const short8* PB = (const short8*)P + (size_t)jc*ROUNDS*512 + lane;

  f32x4 acc0[8], acc1[8];
  #pragma unroll
  for(int c=0;c<8;c++){ acc0[c] = (f32x4){0,0,0,0}; acc1[c] = (f32x4){0,0,0,0}; }
  float den0 = 0.f, den1 = 0.f;

  auto wcalc = [&](unsigned int bits, float4 fa, float4 fb,
                   float rf1, float& den) -> short8 {
    short8 af; float t, w;
    #define WE(slot, fv)                                  \
      t = rf1 + (fv); t = fmaxf(t, ALPHA*t);              \
      w = (bits & (1u<<(slot))) ? __expf(t) : 0.f;        \
      den += w; af[slot] = (short)f2bf(w);
    WE(0,fa.x) WE(1,fa.y) WE(2,fa.z) WE(3,fa.w)
    WE(4,fb.x) WE(5,fb.y) WE(6,fb.z) WE(7,fb.w)
    #undef WE
    return af;
  };

  short8 Bf[8], Bn[8];
  #pragma unroll
  for(int c=0;c<8;c++) Bn[c] = PB[c*64];

  for(int rd=0; rd<ROUNDS; rd++){
    #pragma unroll
    for(int c=0;c<8;c++) Bf[c] = Bn[c];
    if(rd+1 < ROUNDS){
      const short8* Bq = PB + (size_t)(rd+1)*512;
      #pragma unroll
      for(int c=0;c<8;c++) Bn[c] = Bq[c*64];
    }
    unsigned int b0 = (bw0[rd ^ x0] >> (q*8)) & 0xffu;
    unsigned int b1 = (bw1[rd ^ x1] >> (q*8)) & 0xffu;
    float4 fva = *(const float4*)(f2s + rd*32 + q*8);
    float4 fvb = *(const float4*)(f2s + rd*32 + q*8 + 4);
    short8 af0 = wcalc(b0, fva, fvb, rf1a, den0);
    short8 af1 = wcalc(b1, fva, fvb, rf1b, den1);
    #pragma unroll
    for(int c=0;c<8;c++){
      acc0[c] = __builtin_amdgcn_mfma_f32_16x16x32_bf16(af0, Bf[c], acc0[c], 0,0,0);
      acc1[c] = __builtin_amdgcn_mfma_f32_16x16x32_bf16(af1, Bf[c], acc1[c], 0,0,0);
    }
  }

  // den: lanes m,m+16,m+32,m+48 hold q-partials of row m
  den0 += __shfl_down(den0, 32); den0 += __shfl_down(den0, 16);
  den1 += __shfl_down(den1, 32); den1 += __shfl_down(den1, 16);
  const int r0w = r0b + wave*32;
  if(lane < 16){
    denp[(size_t)jc*N_NODES + r0w + lane]      = den0;
    denp[(size_t)jc*N_NODES + r0w + 16 + lane] = den1;
  }
  // C/D layout: col = c*16 + m, row = q*4 + reg (verified R1-R5)
  float* pp = part + (size_t)jc*N_NODES*OUT_F;
  #pragma unroll
  for(int c=0;c<8;c++){
    #pragma unroll
    for(int reg=0;reg<4;reg++){
      pp[(size_t)(r0w + q*4 + reg)*OUT_F      + c*16 + m] = acc0[c][reg];
      pp[(size_t)(r0w + 16 + q*4 + reg)*OUT_F + c*16 + m] = acc1[c][reg];
    }
  }
}

// ---------------- K4: out = elu(sum(parts)/sum(dens)) ----------------
__global__ __launch_bounds__(256) void k_out(const float* __restrict__ part,
    const float* __restrict__ denp, float* __restrict__ out){
  const int idx = blockIdx.x*256 + threadIdx.x;
  const int r = idx >> 7;
  float v = 0.f, d = 0.f;
  #pragma unroll
  for(int p=0;p<JC;p++){
    v += part[(size_t)p*N_NODES*OUT_F + idx];
    d += denp[(size_t)p*N_NODES + r];
  }
  v /= d;
  out[idx] = v > 0.f ? v : (__expf(v) - 1.f);
}

extern "C" void kernel_launch(void* const* d_in, const int* in_sizes, int n_in,
                              void* d_out, int out_size, void* d_ws, size_t ws_size,
                              hipStream_t stream){
  const float* x   = (const float*)d_in[0];
  const int*   adj = (const int*)d_in[1];
  const float* W   = (const float*)d_in[2];
  const float* a   = (const float*)d_in[3];
  char* ws = (char*)d_ws;
  // ws: [0,4M) h | [4,6M) P | 6M: f1,f2 | [8,40M) parts | [40M,+256K) dens |
  //     [48,56M) bitmask
  float* h            = (float*)ws;
  unsigned short* P   = (unsigned short*)(ws + (4u<<20));
  float* f1           = (float*)(ws + (6u<<20));
  float* f2           = (float*)(ws + (6u<<20) + (32u<<10));
  float* part         = (float*)(ws + (8u<<20));
  float* denp         = (float*)(ws + (40u<<20));
  unsigned long long* bm = (unsigned long long*)(ws + (48u<<20));
  float* out          = (float*)d_out;

  k_comp<<<2048, 256, 0, stream>>>(adj, bm);
  k_h<<<512, 256, 0, stream>>>(x, W, h);
  k_f<<<2048, 256, 0, stream>>>(h, a, f1, f2);
  k_pack<<<256, 256, 0, stream>>>(h, P);
  k_attn<<<dim3(JC,64), 256, 0, stream>>>((const unsigned int*)bm, P, f1, f2, part, denp);
  k_out<<<(N_NODES*OUT_F)/256, 256, 0, stream>>>(part, denp, out);
}